// Round 1
// baseline (1204.196 us; speedup 1.0000x reference)
//
#include <hip/hip_runtime.h>

typedef __bf16 bf16x8 __attribute__((ext_vector_type(8)));
typedef float f32x4 __attribute__((ext_vector_type(4)));
typedef unsigned short us8 __attribute__((ext_vector_type(8)));
typedef unsigned short us4 __attribute__((ext_vector_type(4)));

#define HIDN 768
#define NHEAD 12
#define HDIM 64
#define FFDIM 3072
#define NCAND 8

__device__ __forceinline__ float bf2f(unsigned short u) {
    union { unsigned int i; float f; } x; x.i = ((unsigned int)u) << 16; return x.f;
}
__device__ __forceinline__ unsigned short f2bf(float f) {
    __bf16 h = (__bf16)f;
    return __builtin_bit_cast(unsigned short, h);
}

// ---------------- conversion kernels ----------------
__global__ __launch_bounds__(256) void cvt_f2b(const float* __restrict__ src,
                                               unsigned short* __restrict__ dst, long n4) {
    long i = (long)blockIdx.x * 256 + threadIdx.x;
    if (i >= n4) return;
    float4 f = ((const float4*)src)[i];
    us4 o; o[0] = f2bf(f.x); o[1] = f2bf(f.y); o[2] = f2bf(f.z); o[3] = f2bf(f.w);
    *(us4*)&dst[i * 4] = o;
}

// Wk2[h][j][d] = Wk[(h*64+d)*768 + j]   (per-head transposed for the qk GEMM)
__global__ __launch_bounds__(256) void cvt_wk(const float* __restrict__ Wk,
                                              unsigned short* __restrict__ Wk2) {
    int i = blockIdx.x * 256 + threadIdx.x;
    if (i >= NHEAD * HIDN * HDIM) return;
    int h = i / (HIDN * HDIM);
    int rem = i - h * (HIDN * HDIM);
    int j = rem >> 6, d = rem & 63;
    Wk2[i] = f2bf(Wk[(long)(h * 64 + d) * HIDN + j]);
}

// ---------------- mask dtype detection ----------------
// classify storage of the bool mask: 0=int32, 1=bytes(bool/int8), 2=float32, 3=int64
__global__ void mask_detect(const unsigned char* __restrict__ m, int nbytes, int* __restrict__ mode) {
    __shared__ int fl[3]; // [0]: nz at j%4==1 ; [1]: nz at j%4 in {2,3} ; [2]: nz at j%8==4
    if (threadIdx.x < 3) fl[threadIdx.x] = 0;
    __syncthreads();
    int a0 = 0, a1 = 0, a2 = 0;
    for (int i = threadIdx.x; i < nbytes; i += 256) {
        if (m[i]) {
            int r4 = i & 3, r8 = i & 7;
            if (r4 == 1) a0 = 1;
            if (r4 >= 2) a1 = 1;
            if (r8 == 4) a2 = 1;
        }
    }
    if (a0) fl[0] = 1;
    if (a1) fl[1] = 1;
    if (a2) fl[2] = 1;
    __syncthreads();
    if (threadIdx.x == 0) {
        int md;
        if (fl[0]) md = 1;
        else if (fl[1]) md = 2;
        else if (fl[2]) md = 0;
        else md = 3;
        *mode = md;
    }
}

// ---------------- generic MFMA GEMM: C(M,N) = A(M,K) @ B(N,K)^T + bias ----------------
// 64x64 tile, 256 threads (4 waves in 2x2), 16x16x32 bf16 MFMA, single-buffered LDS.
template <bool OUT_BF16, bool GELU, bool FLAG>
__global__ __launch_bounds__(256) void gemm_bt(
    const unsigned short* __restrict__ A, const unsigned short* __restrict__ B,
    void* __restrict__ Cv, const float* __restrict__ bias, const float* __restrict__ flag,
    int N, int K, int lda, int ldc,
    long a_z, long b_z, long c_z, int bias_z) {
    const int z = blockIdx.z;
    A += (long)z * a_z;
    B += (long)z * b_z;
    const int tid = threadIdx.x;
    const int m0 = blockIdx.y * 64, n0 = blockIdx.x * 64;
    __shared__ __attribute__((aligned(16))) unsigned short As[64][72];
    __shared__ __attribute__((aligned(16))) unsigned short Bs[64][72];
    f32x4 acc[2][2] = {};
    const int lane = tid & 63, w = tid >> 6;
    const int wm = w & 1, wn = w >> 1;
    const int ar = tid >> 3;        // 0..31, + r*32
    const int ac = (tid & 7) * 8;   // 0..56 step 8

    for (int k0 = 0; k0 < K; k0 += 64) {
#pragma unroll
        for (int r = 0; r < 2; r++) {
            int row = ar + r * 32;
            us8 av = *(const us8*)&A[(long)(m0 + row) * lda + k0 + ac];
            *(us8*)&As[row][ac] = av;
            us8 bv = *(const us8*)&B[(long)(n0 + row) * K + k0 + ac];
            *(us8*)&Bs[row][ac] = bv;
        }
        __syncthreads();
#pragma unroll
        for (int kk = 0; kk < 64; kk += 32) {
            int kf = kk + (lane >> 4) * 8;
            bf16x8 a0 = *(const bf16x8*)&As[wm * 32 + (lane & 15)][kf];
            bf16x8 a1 = *(const bf16x8*)&As[wm * 32 + 16 + (lane & 15)][kf];
            bf16x8 b0 = *(const bf16x8*)&Bs[wn * 32 + (lane & 15)][kf];
            bf16x8 b1 = *(const bf16x8*)&Bs[wn * 32 + 16 + (lane & 15)][kf];
            acc[0][0] = __builtin_amdgcn_mfma_f32_16x16x32_bf16(a0, b0, acc[0][0], 0, 0, 0);
            acc[0][1] = __builtin_amdgcn_mfma_f32_16x16x32_bf16(a0, b1, acc[0][1], 0, 0, 0);
            acc[1][0] = __builtin_amdgcn_mfma_f32_16x16x32_bf16(a1, b0, acc[1][0], 0, 0, 0);
            acc[1][1] = __builtin_amdgcn_mfma_f32_16x16x32_bf16(a1, b1, acc[1][1], 0, 0, 0);
        }
        __syncthreads();
    }

    float* Cf = (float*)Cv;
    unsigned short* Ch = (unsigned short*)Cv;
    const long cbase = (long)z * c_z;
#pragma unroll
    for (int tm = 0; tm < 2; tm++)
#pragma unroll
        for (int tn = 0; tn < 2; tn++) {
            int col = n0 + wn * 32 + tn * 16 + (lane & 15);
            int rbase = m0 + wm * 32 + tm * 16 + ((lane >> 4) * 4);
            float bb = bias ? bias[(long)z * bias_z + col] : 0.f;
#pragma unroll
            for (int r = 0; r < 4; r++) {
                int row = rbase + r;
                float v = acc[tm][tn][r] + bb;
                if (GELU) v = 0.5f * v * (1.f + erff(v * 0.70710678118654752f));
                if (FLAG) v *= flag[row];
                long off = cbase + (long)row * ldc + col;
                if (OUT_BF16) Ch[off] = f2bf(v);
                else Cf[off] = v;
            }
        }
}

// ---------------- qbk[t,h] = sum_d q[t,h,d] * bk[h*64+d] ----------------
__global__ __launch_bounds__(256) void qbk_kernel(const unsigned short* __restrict__ Qb,
                                                  const float* __restrict__ bk,
                                                  float* __restrict__ qbk, long npair) {
    int lane = threadIdx.x & 63, w = threadIdx.x >> 6;
    long p = (long)blockIdx.x * 4 + w;
    if (p >= npair) return;
    long t = p / 12;
    int h = (int)(p - t * 12);
    float v = bf2f(Qb[t * HIDN + h * 64 + lane]) * bk[h * 64 + lane];
    for (int o = 32; o; o >>= 1) v += __shfl_down(v, o);
    if (lane == 0) qbk[p] = v;
}

// ---------------- fused attention: scores -> softmax -> cw (in-place over qk buffer) ----
__global__ __launch_bounds__(256) void attn_kernel(
    const float* __restrict__ cands, unsigned short* __restrict__ qkcw,
    const void* __restrict__ maskp, const int* __restrict__ mode,
    const float* __restrict__ qbk, float* __restrict__ allm, long t0) {
    const int tid = threadIdx.x;
    const long tl = blockIdx.x;
    const long t = t0 + tl;
    __shared__ __attribute__((aligned(16))) float c_s[NCAND][HIDN];   // 24 KB
    __shared__ __attribute__((aligned(16))) float qk_s[NHEAD][HIDN];  // 36 KB
    __shared__ float sc[NHEAD][NCAND];
    __shared__ float attn_s[NHEAD][NCAND];
    __shared__ int msk[NCAND];
    __shared__ float qb_s[NHEAD];

    const float4* c4 = (const float4*)(cands + t * NCAND * HIDN);
    float4* cs4 = (float4*)&c_s[0][0];
    for (int i = tid; i < NCAND * HIDN / 4; i += 256) cs4[i] = c4[i];

    const us8* q8 = (const us8*)(qkcw + tl * (NHEAD * HIDN));
    for (int i = tid; i < NHEAD * HIDN / 8; i += 256) {
        us8 v = q8[i];
        float* dst = &qk_s[0][0] + i * 8;
#pragma unroll
        for (int j = 0; j < 8; j++) dst[j] = bf2f(v[j]);
    }
    if (tid < NCAND) {
        int mm = *mode;
        long mi = t * NCAND + tid;
        int mv;
        if (mm == 1)      mv = ((const unsigned char*)maskp)[mi] != 0;
        else if (mm == 2) mv = ((const float*)maskp)[mi] != 0.f;
        else if (mm == 3) mv = ((const long long*)maskp)[mi] != 0;
        else              mv = ((const int*)maskp)[mi] != 0;
        msk[tid] = mv;
    }
    if (tid >= 32 && tid < 32 + NHEAD) qb_s[tid - 32] = qbk[tl * NHEAD + (tid - 32)];
    __syncthreads();

    const int lane = tid & 63, w = tid >> 6;
    for (int p = w; p < NHEAD * NCAND; p += 4) {
        int h = p >> 3, n = p & 7;
        float s = 0.f;
        for (int j = lane; j < HIDN; j += 64) s += qk_s[h][j] * c_s[n][j];
        for (int o = 32; o; o >>= 1) s += __shfl_down(s, o);
        if (lane == 0) sc[h][n] = msk[n] ? 1e-10f : (s + qb_s[h]) * 0.125f;
    }
    __syncthreads();

    if (tid < NHEAD) {
        int h = tid;
        float mx = -1e30f;
        for (int n = 0; n < NCAND; n++) mx = fmaxf(mx, sc[h][n]);
        float e[NCAND], sm = 0.f;
        for (int n = 0; n < NCAND; n++) { e[n] = expf(sc[h][n] - mx); sm += e[n]; }
        float inv = 1.f / sm;
        for (int n = 0; n < NCAND; n++) attn_s[h][n] = e[n] * inv;
    }
    if (tid == 128) {
        int a = 1;
        for (int n = 0; n < NCAND; n++) a &= msk[n];
        allm[tl] = a ? 0.f : 1.f;
    }
    __syncthreads();

    unsigned short* out = qkcw + tl * (NHEAD * HIDN);
    for (int idx = tid; idx < NHEAD * HIDN; idx += 256) {
        int h = idx / HIDN, j = idx - h * HIDN;
        float v = 0.f;
#pragma unroll
        for (int n = 0; n < NCAND; n++) v += attn_s[h][n] * c_s[n][j];
        out[idx] = f2bf(v);
    }
}

// ---------------- residual + layernorm (in-place on d_out region) ----------------
__global__ __launch_bounds__(256) void ln_kernel(float* __restrict__ io, const float* __restrict__ x,
                                                 const float* __restrict__ gamma,
                                                 const float* __restrict__ beta, long t0) {
    const int tid = threadIdx.x;
    const long tl = blockIdx.x;
    const long t = t0 + tl;
    float* row = io + tl * HIDN;
    const float* xr = x + t * HIDN;
    float v[3];
#pragma unroll
    for (int i = 0; i < 3; i++) v[i] = row[tid + i * 256] + xr[tid + i * 256];
    __shared__ float red[4];
    const int lane = tid & 63, w = tid >> 6;
    float s = v[0] + v[1] + v[2];
    for (int o = 32; o; o >>= 1) s += __shfl_down(s, o);
    if (lane == 0) red[w] = s;
    __syncthreads();
    float mu = (red[0] + red[1] + red[2] + red[3]) * (1.f / HIDN);
    __syncthreads();
    float d0 = v[0] - mu, d1 = v[1] - mu, d2 = v[2] - mu;
    float q = d0 * d0 + d1 * d1 + d2 * d2;
    for (int o = 32; o; o >>= 1) q += __shfl_down(q, o);
    if (lane == 0) red[w] = q;
    __syncthreads();
    float var = (red[0] + red[1] + red[2] + red[3]) * (1.f / HIDN);
    float inv = rsqrtf(var + 1e-12f);
#pragma unroll
    for (int i = 0; i < 3; i++) {
        int j = tid + i * 256;
        row[j] = (v[i] - mu) * inv * gamma[j] + beta[j];
    }
}

// ---------------- launcher ----------------
extern "C" void kernel_launch(void* const* d_in, const int* in_sizes, int n_in,
                              void* d_out, int out_size, void* d_ws, size_t ws_size,
                              hipStream_t stream) {
    const float* x     = (const float*)d_in[0];
    const float* cands = (const float*)d_in[1];
    const void*  maskp = d_in[2];
    const float* Wq = (const float*)d_in[3];
    const float* bq = (const float*)d_in[4];
    const float* Wk = (const float*)d_in[5];
    const float* bk = (const float*)d_in[6];
    const float* Wv = (const float*)d_in[7];
    const float* bv = (const float*)d_in[8];
    const float* Wt = (const float*)d_in[9];
    const float* bt = (const float*)d_in[10];
    const float* Wc = (const float*)d_in[11];
    const float* bc = (const float*)d_in[12];
    const float* gamma = (const float*)d_in[13];
    const float* beta  = (const float*)d_in[14];
    float* out = (float*)d_out;

    const long T = (long)in_sizes[0] / HIDN;  // 8192

    // ---- carve workspace ----
    char* p = (char*)d_ws;
    auto alloc = [&](size_t bytes) -> char* {
        char* r = p;
        p += (bytes + 255) & ~(size_t)255;
        return r;
    };
    unsigned short* Wqb  = (unsigned short*)alloc((size_t)HIDN * HIDN * 2);
    unsigned short* Wk2b = (unsigned short*)alloc((size_t)HIDN * HIDN * 2);
    unsigned short* Wvb  = (unsigned short*)alloc((size_t)HIDN * HIDN * 2);
    unsigned short* Wtb  = (unsigned short*)alloc((size_t)FFDIM * HIDN * 2);
    unsigned short* Wcb  = (unsigned short*)alloc((size_t)HIDN * FFDIM * 2);
    int* mode = (int*)alloc(256);
    size_t fixed = (size_t)(p - (char*)d_ws);

    long TC = T;
    auto chunk_bytes = [&](long tc) -> size_t {
        return (size_t)tc * (HIDN * 2 /*Xb*/ + HIDN * 2 /*Qb*/ + NHEAD * 4 /*qbk*/ + 4 /*allm*/ +
                             HIDN * 2 /*CTXb*/ + NHEAD * HIDN * 2 /*BIG*/) + 8 * 256;
    };
    while (TC > 512 && fixed + chunk_bytes(TC) > ws_size) TC >>= 1;

    unsigned short* Xb   = (unsigned short*)alloc((size_t)TC * HIDN * 2);
    unsigned short* Qb   = (unsigned short*)alloc((size_t)TC * HIDN * 2);
    float* qbkb          = (float*)alloc((size_t)TC * NHEAD * 4);
    float* allm          = (float*)alloc((size_t)TC * 4);
    unsigned short* CTXb = (unsigned short*)alloc((size_t)TC * HIDN * 2);
    unsigned short* BIG  = (unsigned short*)alloc((size_t)TC * NHEAD * HIDN * 2); // qk / cw / h1

    // ---- weight conversions (once per call) ----
    {
        long n4;
        n4 = (long)HIDN * HIDN / 4;
        cvt_f2b<<<dim3((n4 + 255) / 256), 256, 0, stream>>>(Wq, Wqb, n4);
        cvt_f2b<<<dim3((n4 + 255) / 256), 256, 0, stream>>>(Wv, Wvb, n4);
        n4 = (long)FFDIM * HIDN / 4;
        cvt_f2b<<<dim3((n4 + 255) / 256), 256, 0, stream>>>(Wt, Wtb, n4);
        cvt_f2b<<<dim3((n4 + 255) / 256), 256, 0, stream>>>(Wc, Wcb, n4);
        int nwk = NHEAD * HIDN * HDIM;
        cvt_wk<<<dim3((nwk + 255) / 256), 256, 0, stream>>>(Wk, Wk2b);
        mask_detect<<<dim3(1), 256, 0, stream>>>((const unsigned char*)maskp, (int)(T * NCAND), mode);
    }

    for (long t0 = 0; t0 < T; t0 += TC) {
        long n4 = TC * HIDN / 4;
        cvt_f2b<<<dim3((n4 + 255) / 256), 256, 0, stream>>>(x + t0 * HIDN, Xb, n4);

        // G1: Q = X @ Wq^T + bq     (TC x 768, K=768)
        gemm_bt<true, false, false><<<dim3(HIDN / 64, TC / 64, 1), 256, 0, stream>>>(
            Xb, Wqb, Qb, bq, nullptr, HIDN, HIDN, HIDN, HIDN, 0, 0, 0, 0);

        qbk_kernel<<<dim3((TC * NHEAD + 3) / 4), 256, 0, stream>>>(Qb, bk, qbkb, TC * NHEAD);

        // G2: qk_h = Q_h @ Wk_h    (per head: TC x 768, K=64)
        gemm_bt<true, false, false><<<dim3(HIDN / 64, TC / 64, NHEAD), 256, 0, stream>>>(
            Qb, Wk2b, BIG, nullptr, nullptr, HIDN, HDIM, HIDN, NHEAD * HIDN,
            HDIM, (long)HIDN * HDIM, HIDN, 0);

        // fused attention: scores -> softmax -> cw (overwrites qk rows)
        attn_kernel<<<dim3(TC), 256, 0, stream>>>(cands, BIG, maskp, mode, qbkb, allm, t0);

        // G5: ctx_h = cw_h @ Wv_h^T + bv_h, zeroed if all-masked  (per head: TC x 64, K=768)
        gemm_bt<true, false, true><<<dim3(1, TC / 64, NHEAD), 256, 0, stream>>>(
            BIG, Wvb, CTXb, bv, allm, HDIM, HIDN, NHEAD * HIDN, HIDN,
            HIDN, (long)HDIM * HIDN, HDIM, HDIM);

        // G6: h1 = gelu(ctx @ Wt^T + bt)   (TC x 3072, K=768) -> BIG
        gemm_bt<true, true, false><<<dim3(FFDIM / 64, TC / 64, 1), 256, 0, stream>>>(
            CTXb, Wtb, BIG, bt, nullptr, FFDIM, HIDN, HIDN, FFDIM, 0, 0, 0, 0);

        // G7: ctx2 = h1 @ Wc^T + bc  -> d_out (fp32)
        gemm_bt<false, false, false><<<dim3(HIDN / 64, TC / 64, 1), 256, 0, stream>>>(
            BIG, Wcb, out + t0 * HIDN, bc, nullptr, HIDN, FFDIM, FFDIM, HIDN, 0, 0, 0, 0);

        // residual + layernorm, in place
        ln_kernel<<<dim3(TC), 256, 0, stream>>>(out + t0 * HIDN, x, gamma, beta, t0);
    }
}

// Round 2
// 874.872 us; speedup vs baseline: 1.3764x; 1.3764x over previous
//
#include <hip/hip_runtime.h>

typedef __bf16 bf16x8 __attribute__((ext_vector_type(8)));
typedef float f32x4 __attribute__((ext_vector_type(4)));
typedef unsigned short us8 __attribute__((ext_vector_type(8)));
typedef unsigned short us4 __attribute__((ext_vector_type(4)));

#define HIDN 768
#define NHEAD 12
#define HDIM 64
#define FFDIM 3072
#define NCAND 8

__device__ __forceinline__ float bf2f(unsigned short u) {
    union { unsigned int i; float f; } x; x.i = ((unsigned int)u) << 16; return x.f;
}
__device__ __forceinline__ unsigned short f2bf(float f) {
    __bf16 h = (__bf16)f;
    return __builtin_bit_cast(unsigned short, h);
}
__device__ __forceinline__ float lo_bf(unsigned int u) {
    union { unsigned int i; float f; } x; x.i = u << 16; return x.f;
}
__device__ __forceinline__ float hi_bf(unsigned int u) {
    union { unsigned int i; float f; } x; x.i = u & 0xffff0000u; return x.f;
}

// ---------------- conversion kernels ----------------
__global__ __launch_bounds__(256) void cvt_f2b(const float* __restrict__ src,
                                               unsigned short* __restrict__ dst, long n4) {
    long i = (long)blockIdx.x * 256 + threadIdx.x;
    if (i >= n4) return;
    float4 f = ((const float4*)src)[i];
    us4 o; o[0] = f2bf(f.x); o[1] = f2bf(f.y); o[2] = f2bf(f.z); o[3] = f2bf(f.w);
    *(us4*)&dst[i * 4] = o;
}

// Wk2[h][j][d] = Wk[(h*64+d)*768 + j]   (per-head transposed for the qk GEMM)
__global__ __launch_bounds__(256) void cvt_wk(const float* __restrict__ Wk,
                                              unsigned short* __restrict__ Wk2) {
    int i = blockIdx.x * 256 + threadIdx.x;
    if (i >= NHEAD * HIDN * HDIM) return;
    int h = i / (HIDN * HDIM);
    int rem = i - h * (HIDN * HDIM);
    int j = rem >> 6, d = rem & 63;
    Wk2[i] = f2bf(Wk[(long)(h * 64 + d) * HIDN + j]);
}

// ---------------- mask dtype detection ----------------
// classify storage of the bool mask: 0=int32, 1=bytes(bool/int8), 2=float32, 3=int64
__global__ void mask_detect(const unsigned char* __restrict__ m, int nbytes, int* __restrict__ mode) {
    __shared__ int fl[3];
    if (threadIdx.x < 3) fl[threadIdx.x] = 0;
    __syncthreads();
    int a0 = 0, a1 = 0, a2 = 0;
    for (int i = threadIdx.x; i < nbytes; i += 256) {
        if (m[i]) {
            int r4 = i & 3, r8 = i & 7;
            if (r4 == 1) a0 = 1;
            if (r4 >= 2) a1 = 1;
            if (r8 == 4) a2 = 1;
        }
    }
    if (a0) fl[0] = 1;
    if (a1) fl[1] = 1;
    if (a2) fl[2] = 1;
    __syncthreads();
    if (threadIdx.x == 0) {
        int md;
        if (fl[0]) md = 1;
        else if (fl[1]) md = 2;
        else if (fl[2]) md = 0;
        else md = 3;
        *mode = md;
    }
}

// ---------------- generic MFMA GEMM: C(M,N) = A(M,K) @ B(N,K)^T + bias ----------------
template <bool OUT_BF16, bool GELU, bool FLAG>
__global__ __launch_bounds__(256) void gemm_bt(
    const unsigned short* __restrict__ A, const unsigned short* __restrict__ B,
    void* __restrict__ Cv, const float* __restrict__ bias, const float* __restrict__ flag,
    int N, int K, int lda, int ldc,
    long a_z, long b_z, long c_z, int bias_z) {
    const int z = blockIdx.z;
    A += (long)z * a_z;
    B += (long)z * b_z;
    const int tid = threadIdx.x;
    const int m0 = blockIdx.y * 64, n0 = blockIdx.x * 64;
    __shared__ __attribute__((aligned(16))) unsigned short As[64][72];
    __shared__ __attribute__((aligned(16))) unsigned short Bs[64][72];
    f32x4 acc[2][2] = {};
    const int lane = tid & 63, w = tid >> 6;
    const int wm = w & 1, wn = w >> 1;
    const int ar = tid >> 3;
    const int ac = (tid & 7) * 8;

    for (int k0 = 0; k0 < K; k0 += 64) {
#pragma unroll
        for (int r = 0; r < 2; r++) {
            int row = ar + r * 32;
            us8 av = *(const us8*)&A[(long)(m0 + row) * lda + k0 + ac];
            *(us8*)&As[row][ac] = av;
            us8 bv = *(const us8*)&B[(long)(n0 + row) * K + k0 + ac];
            *(us8*)&Bs[row][ac] = bv;
        }
        __syncthreads();
#pragma unroll
        for (int kk = 0; kk < 64; kk += 32) {
            int kf = kk + (lane >> 4) * 8;
            bf16x8 a0 = *(const bf16x8*)&As[wm * 32 + (lane & 15)][kf];
            bf16x8 a1 = *(const bf16x8*)&As[wm * 32 + 16 + (lane & 15)][kf];
            bf16x8 b0 = *(const bf16x8*)&Bs[wn * 32 + (lane & 15)][kf];
            bf16x8 b1 = *(const bf16x8*)&Bs[wn * 32 + 16 + (lane & 15)][kf];
            acc[0][0] = __builtin_amdgcn_mfma_f32_16x16x32_bf16(a0, b0, acc[0][0], 0, 0, 0);
            acc[0][1] = __builtin_amdgcn_mfma_f32_16x16x32_bf16(a0, b1, acc[0][1], 0, 0, 0);
            acc[1][0] = __builtin_amdgcn_mfma_f32_16x16x32_bf16(a1, b0, acc[1][0], 0, 0, 0);
            acc[1][1] = __builtin_amdgcn_mfma_f32_16x16x32_bf16(a1, b1, acc[1][1], 0, 0, 0);
        }
        __syncthreads();
    }

    float* Cf = (float*)Cv;
    unsigned short* Ch = (unsigned short*)Cv;
    const long cbase = (long)z * c_z;
#pragma unroll
    for (int tm = 0; tm < 2; tm++)
#pragma unroll
        for (int tn = 0; tn < 2; tn++) {
            int col = n0 + wn * 32 + tn * 16 + (lane & 15);
            int rbase = m0 + wm * 32 + tm * 16 + ((lane >> 4) * 4);
            float bb = bias ? bias[(long)z * bias_z + col] : 0.f;
#pragma unroll
            for (int r = 0; r < 4; r++) {
                int row = rbase + r;
                float v = acc[tm][tn][r] + bb;
                if (GELU) v = 0.5f * v * (1.f + erff(v * 0.70710678118654752f));
                if (FLAG) v *= flag[row];
                long off = cbase + (long)row * ldc + col;
                if (OUT_BF16) Ch[off] = f2bf(v);
                else Cf[off] = v;
            }
        }
}

// ---------------- qbk[t,h] = sum_d q[t,h,d] * bk[h*64+d] ----------------
__global__ __launch_bounds__(256) void qbk_kernel(const unsigned short* __restrict__ Qb,
                                                  const float* __restrict__ bk,
                                                  float* __restrict__ qbk, long npair) {
    int lane = threadIdx.x & 63, w = threadIdx.x >> 6;
    long p = (long)blockIdx.x * 4 + w;
    if (p >= npair) return;
    long t = p / 12;
    int h = (int)(p - t * 12);
    float v = bf2f(Qb[t * HIDN + h * 64 + lane]) * bk[h * 64 + lane];
    for (int o = 32; o; o >>= 1) v += __shfl_down(v, o);
    if (lane == 0) qbk[p] = v;
}

// ---------------- fused attention v2: all-bf16 LDS, low footprint ----------------
// scores -> softmax -> cw (in-place over qk buffer)
#define LDP 776  // padded row stride (elems); 776*2=1552 B, 16B-aligned rows
__global__ __launch_bounds__(256) void attn_kernel(
    const float* __restrict__ cands, unsigned short* __restrict__ qkcw,
    const void* __restrict__ maskp, const int* __restrict__ mode,
    const float* __restrict__ qbk, float* __restrict__ allm, long t0) {
    const int tid = threadIdx.x;
    const long tl = blockIdx.x;
    const long t = t0 + tl;
    __shared__ __attribute__((aligned(16))) unsigned short c_s[NCAND][LDP];   // ~12.4 KB
    __shared__ __attribute__((aligned(16))) unsigned short qk_s[NHEAD][LDP];  // ~18.6 KB
    __shared__ float sc[NHEAD][NCAND];
    __shared__ float attn_s[NHEAD][NCAND];
    __shared__ int msk[NCAND];
    __shared__ float qb_s[NHEAD];

    // stage c: fp32 global -> bf16 LDS (fused convert, us4 stores: 8B-aligned, conflict-free)
    const float4* c4 = (const float4*)(cands + t * NCAND * HIDN);
    for (int i = tid; i < NCAND * HIDN / 4; i += 256) {
        int n = i / (HIDN / 4), j4 = (i - n * (HIDN / 4)) * 4;
        float4 f = c4[i];
        us4 o; o[0] = f2bf(f.x); o[1] = f2bf(f.y); o[2] = f2bf(f.z); o[3] = f2bf(f.w);
        *(us4*)&c_s[n][j4] = o;
    }
    // stage qk: bf16 straight copy (us8 = b128, rows 16B-aligned)
    const us8* q8 = (const us8*)(qkcw + tl * (NHEAD * HIDN));
    for (int i = tid; i < NHEAD * HIDN / 8; i += 256) {
        int h = i / (HIDN / 8), j8 = (i - h * (HIDN / 8)) * 8;
        *(us8*)&qk_s[h][j8] = q8[i];
    }
    if (tid < NCAND) {
        int mm = *mode;
        long mi = t * NCAND + tid;
        int mv;
        if (mm == 1)      mv = ((const unsigned char*)maskp)[mi] != 0;
        else if (mm == 2) mv = ((const float*)maskp)[mi] != 0.f;
        else if (mm == 3) mv = ((const long long*)maskp)[mi] != 0;
        else              mv = ((const int*)maskp)[mi] != 0;
        msk[tid] = mv;
    }
    if (tid >= 64 && tid < 64 + NHEAD) qb_s[tid - 64] = qbk[tl * NHEAD + (tid - 64)];
    __syncthreads();

    // scores: 96 (h,n) pairs over 4 waves; packed-b32 LDS reads, lane-consecutive -> conflict-free
    const int lane = tid & 63, w = tid >> 6;
    for (int p = w; p < NHEAD * NCAND; p += 4) {
        int h = p >> 3, n = p & 7;
        float s = 0.f;
#pragma unroll
        for (int i = 0; i < 6; i++) {
            int j = 2 * lane + 128 * i;
            unsigned int ua = *(const unsigned int*)&qk_s[h][j];
            unsigned int ub = *(const unsigned int*)&c_s[n][j];
            s += lo_bf(ua) * lo_bf(ub) + hi_bf(ua) * hi_bf(ub);
        }
        for (int o = 32; o; o >>= 1) s += __shfl_down(s, o);
        if (lane == 0) sc[h][n] = msk[n] ? 1e-10f : (s + qb_s[h]) * 0.125f;
    }
    __syncthreads();

    if (tid < NHEAD) {
        int h = tid;
        float mx = -1e30f;
        for (int n = 0; n < NCAND; n++) mx = fmaxf(mx, sc[h][n]);
        float e[NCAND], sm = 0.f;
        for (int n = 0; n < NCAND; n++) { e[n] = expf(sc[h][n] - mx); sm += e[n]; }
        float inv = 1.f / sm;
        for (int n = 0; n < NCAND; n++) attn_s[h][n] = e[n] * inv;
    }
    if (tid == 64) {
        int a = 1;
        for (int n = 0; n < NCAND; n++) a &= msk[n];
        allm[tl] = a ? 0.f : 1.f;
    }
    __syncthreads();

    // cw: out[h][j..j+7] = sum_n attn[h][n] * c[n][j..j+7]; b128 LDS reads, coalesced global us8 store
    unsigned short* out = qkcw + tl * (NHEAD * HIDN);
    for (int i = tid; i < NHEAD * HIDN / 8; i += 256) {
        int h = i / (HIDN / 8), j8 = (i - h * (HIDN / 8)) * 8;
        float acc[8] = {0.f, 0.f, 0.f, 0.f, 0.f, 0.f, 0.f, 0.f};
#pragma unroll
        for (int n = 0; n < NCAND; n++) {
            us8 cv = *(const us8*)&c_s[n][j8];
            float a = attn_s[h][n];
#pragma unroll
            for (int k = 0; k < 8; k++) acc[k] += a * bf2f(cv[k]);
        }
        us8 o;
#pragma unroll
        for (int k = 0; k < 8; k++) o[k] = f2bf(acc[k]);
        ((us8*)out)[i] = o;
    }
}

// ---------------- residual + layernorm (in-place on d_out region) ----------------
__global__ __launch_bounds__(256) void ln_kernel(float* __restrict__ io, const float* __restrict__ x,
                                                 const float* __restrict__ gamma,
                                                 const float* __restrict__ beta, long t0) {
    const int tid = threadIdx.x;
    const long tl = blockIdx.x;
    const long t = t0 + tl;
    float* row = io + tl * HIDN;
    const float* xr = x + t * HIDN;
    float v[3];
#pragma unroll
    for (int i = 0; i < 3; i++) v[i] = row[tid + i * 256] + xr[tid + i * 256];
    __shared__ float red[4];
    const int lane = tid & 63, w = tid >> 6;
    float s = v[0] + v[1] + v[2];
    for (int o = 32; o; o >>= 1) s += __shfl_down(s, o);
    if (lane == 0) red[w] = s;
    __syncthreads();
    float mu = (red[0] + red[1] + red[2] + red[3]) * (1.f / HIDN);
    __syncthreads();
    float d0 = v[0] - mu, d1 = v[1] - mu, d2 = v[2] - mu;
    float q = d0 * d0 + d1 * d1 + d2 * d2;
    for (int o = 32; o; o >>= 1) q += __shfl_down(q, o);
    if (lane == 0) red[w] = q;
    __syncthreads();
    float var = (red[0] + red[1] + red[2] + red[3]) * (1.f / HIDN);
    float inv = rsqrtf(var + 1e-12f);
#pragma unroll
    for (int i = 0; i < 3; i++) {
        int j = tid + i * 256;
        row[j] = (v[i] - mu) * inv * gamma[j] + beta[j];
    }
}

// ---------------- launcher ----------------
extern "C" void kernel_launch(void* const* d_in, const int* in_sizes, int n_in,
                              void* d_out, int out_size, void* d_ws, size_t ws_size,
                              hipStream_t stream) {
    const float* x     = (const float*)d_in[0];
    const float* cands = (const float*)d_in[1];
    const void*  maskp = d_in[2];
    const float* Wq = (const float*)d_in[3];
    const float* bq = (const float*)d_in[4];
    const float* Wk = (const float*)d_in[5];
    const float* bk = (const float*)d_in[6];
    const float* Wv = (const float*)d_in[7];
    const float* bv = (const float*)d_in[8];
    const float* Wt = (const float*)d_in[9];
    const float* bt = (const float*)d_in[10];
    const float* Wc = (const float*)d_in[11];
    const float* bc = (const float*)d_in[12];
    const float* gamma = (const float*)d_in[13];
    const float* beta  = (const float*)d_in[14];
    float* out = (float*)d_out;

    const long T = (long)in_sizes[0] / HIDN;  // 8192

    char* p = (char*)d_ws;
    auto alloc = [&](size_t bytes) -> char* {
        char* r = p;
        p += (bytes + 255) & ~(size_t)255;
        return r;
    };
    unsigned short* Wqb  = (unsigned short*)alloc((size_t)HIDN * HIDN * 2);
    unsigned short* Wk2b = (unsigned short*)alloc((size_t)HIDN * HIDN * 2);
    unsigned short* Wvb  = (unsigned short*)alloc((size_t)HIDN * HIDN * 2);
    unsigned short* Wtb  = (unsigned short*)alloc((size_t)FFDIM * HIDN * 2);
    unsigned short* Wcb  = (unsigned short*)alloc((size_t)HIDN * FFDIM * 2);
    int* mode = (int*)alloc(256);
    size_t fixed = (size_t)(p - (char*)d_ws);

    long TC = T;
    auto chunk_bytes = [&](long tc) -> size_t {
        return (size_t)tc * (HIDN * 2 + HIDN * 2 + NHEAD * 4 + 4 +
                             HIDN * 2 + NHEAD * HIDN * 2) + 8 * 256;
    };
    while (TC > 512 && fixed + chunk_bytes(TC) > ws_size) TC >>= 1;

    unsigned short* Xb   = (unsigned short*)alloc((size_t)TC * HIDN * 2);
    unsigned short* Qb   = (unsigned short*)alloc((size_t)TC * HIDN * 2);
    float* qbkb          = (float*)alloc((size_t)TC * NHEAD * 4);
    float* allm          = (float*)alloc((size_t)TC * 4);
    unsigned short* CTXb = (unsigned short*)alloc((size_t)TC * HIDN * 2);
    unsigned short* BIG  = (unsigned short*)alloc((size_t)TC * NHEAD * HIDN * 2);

    {
        long n4;
        n4 = (long)HIDN * HIDN / 4;
        cvt_f2b<<<dim3((n4 + 255) / 256), 256, 0, stream>>>(Wq, Wqb, n4);
        cvt_f2b<<<dim3((n4 + 255) / 256), 256, 0, stream>>>(Wv, Wvb, n4);
        n4 = (long)FFDIM * HIDN / 4;
        cvt_f2b<<<dim3((n4 + 255) / 256), 256, 0, stream>>>(Wt, Wtb, n4);
        cvt_f2b<<<dim3((n4 + 255) / 256), 256, 0, stream>>>(Wc, Wcb, n4);
        int nwk = NHEAD * HIDN * HDIM;
        cvt_wk<<<dim3((nwk + 255) / 256), 256, 0, stream>>>(Wk, Wk2b);
        mask_detect<<<dim3(1), 256, 0, stream>>>((const unsigned char*)maskp, (int)(T * NCAND), mode);
    }

    for (long t0 = 0; t0 < T; t0 += TC) {
        long n4 = TC * HIDN / 4;
        cvt_f2b<<<dim3((n4 + 255) / 256), 256, 0, stream>>>(x + t0 * HIDN, Xb, n4);

        gemm_bt<true, false, false><<<dim3(HIDN / 64, TC / 64, 1), 256, 0, stream>>>(
            Xb, Wqb, Qb, bq, nullptr, HIDN, HIDN, HIDN, HIDN, 0, 0, 0, 0);

        qbk_kernel<<<dim3((TC * NHEAD + 3) / 4), 256, 0, stream>>>(Qb, bk, qbkb, TC * NHEAD);

        gemm_bt<true, false, false><<<dim3(HIDN / 64, TC / 64, NHEAD), 256, 0, stream>>>(
            Qb, Wk2b, BIG, nullptr, nullptr, HIDN, HDIM, HIDN, NHEAD * HIDN,
            HDIM, (long)HIDN * HDIM, HIDN, 0);

        attn_kernel<<<dim3(TC), 256, 0, stream>>>(cands, BIG, maskp, mode, qbkb, allm, t0);

        gemm_bt<true, false, true><<<dim3(1, TC / 64, NHEAD), 256, 0, stream>>>(
            BIG, Wvb, CTXb, bv, allm, HDIM, HIDN, NHEAD * HIDN, HIDN,
            HIDN, (long)HDIM * HIDN, HDIM, HDIM);

        gemm_bt<true, true, false><<<dim3(FFDIM / 64, TC / 64, 1), 256, 0, stream>>>(
            CTXb, Wtb, BIG, bt, nullptr, FFDIM, HIDN, HIDN, FFDIM, 0, 0, 0, 0);

        gemm_bt<false, false, false><<<dim3(HIDN / 64, TC / 64, 1), 256, 0, stream>>>(
            BIG, Wcb, out + t0 * HIDN, bc, nullptr, HIDN, FFDIM, FFDIM, HIDN, 0, 0, 0, 0);

        ln_kernel<<<dim3(TC), 256, 0, stream>>>(out + t0 * HIDN, x, gamma, beta, t0);
    }
}

// Round 3
// 836.544 us; speedup vs baseline: 1.4395x; 1.0458x over previous
//
#include <hip/hip_runtime.h>

typedef __bf16 bf16x8 __attribute__((ext_vector_type(8)));
typedef float f32x4 __attribute__((ext_vector_type(4)));
typedef unsigned short us8 __attribute__((ext_vector_type(8)));
typedef unsigned short us4 __attribute__((ext_vector_type(4)));
typedef unsigned int u32;

#define HIDN 768
#define NHEAD 12
#define HDIM 64
#define FFDIM 3072
#define NCAND 8

__device__ __forceinline__ float bf2f(unsigned short u) {
    union { unsigned int i; float f; } x; x.i = ((unsigned int)u) << 16; return x.f;
}
__device__ __forceinline__ unsigned short f2bf(float f) {
    __bf16 h = (__bf16)f;
    return __builtin_bit_cast(unsigned short, h);
}
__device__ __forceinline__ float lo_bf(unsigned int u) {
    union { unsigned int i; float f; } x; x.i = u << 16; return x.f;
}
__device__ __forceinline__ float hi_bf(unsigned int u) {
    union { unsigned int i; float f; } x; x.i = u & 0xffff0000u; return x.f;
}

typedef const __attribute__((address_space(1))) u32* gas_p;
typedef __attribute__((address_space(3))) u32* las_p;
__device__ __forceinline__ void load_lds16(const unsigned short* g, unsigned short* l) {
    __builtin_amdgcn_global_load_lds((gas_p)(const void*)g, (las_p)(void*)l, 16, 0, 0);
}

// ---------------- conversion kernels ----------------
__global__ __launch_bounds__(256) void cvt_f2b(const float* __restrict__ src,
                                               unsigned short* __restrict__ dst, long n4) {
    long i = (long)blockIdx.x * 256 + threadIdx.x;
    if (i >= n4) return;
    float4 f = ((const float4*)src)[i];
    us4 o; o[0] = f2bf(f.x); o[1] = f2bf(f.y); o[2] = f2bf(f.z); o[3] = f2bf(f.w);
    *(us4*)&dst[i * 4] = o;
}

// Wk2[h][j][d] = Wk[(h*64+d)*768 + j]
__global__ __launch_bounds__(256) void cvt_wk(const float* __restrict__ Wk,
                                              unsigned short* __restrict__ Wk2) {
    int i = blockIdx.x * 256 + threadIdx.x;
    if (i >= NHEAD * HIDN * HDIM) return;
    int h = i / (HIDN * HDIM);
    int rem = i - h * (HIDN * HDIM);
    int j = rem >> 6, d = rem & 63;
    Wk2[i] = f2bf(Wk[(long)(h * 64 + d) * HIDN + j]);
}

// ---------------- mask dtype detection ----------------
__global__ void mask_detect(const unsigned char* __restrict__ m, int nbytes, int* __restrict__ mode) {
    __shared__ int fl[3];
    if (threadIdx.x < 3) fl[threadIdx.x] = 0;
    __syncthreads();
    int a0 = 0, a1 = 0, a2 = 0;
    for (int i = threadIdx.x; i < nbytes; i += 256) {
        if (m[i]) {
            int r4 = i & 3, r8 = i & 7;
            if (r4 == 1) a0 = 1;
            if (r4 >= 2) a1 = 1;
            if (r8 == 4) a2 = 1;
        }
    }
    if (a0) fl[0] = 1;
    if (a1) fl[1] = 1;
    if (a2) fl[2] = 1;
    __syncthreads();
    if (threadIdx.x == 0) {
        int md;
        if (fl[0]) md = 1;
        else if (fl[1]) md = 2;
        else if (fl[2]) md = 0;
        else md = 3;
        *mode = md;
    }
}

// ============ m97-style GEMM: C(M,N) = A(M,K) @ B(N,K)^T + bias ============
// 128x128 tile, BK=64, 256 threads (2x2 waves, each 64x64 = 4x4 MFMA tiles),
// global_load_lds width=16, XOR-swizzled 16B chunks (conflict-free ds_read_b128).
template <bool OUT_BF16, bool GELU>
__global__ __launch_bounds__(256) void gemm128(
    const unsigned short* __restrict__ A, const unsigned short* __restrict__ B,
    void* __restrict__ Cv, const float* __restrict__ bias,
    int K, int lda, int ldb, int ldc,
    long a_z, long b_z, long c_z) {
    const int z = blockIdx.z;
    A += (long)z * a_z;
    B += (long)z * b_z;
    const int tid = threadIdx.x;
    const int m0 = blockIdx.y * 128, n0 = blockIdx.x * 128;
    __shared__ __attribute__((aligned(16))) unsigned short As[128 * 64];
    __shared__ __attribute__((aligned(16))) unsigned short Bs[128 * 64];
    f32x4 acc[4][4] = {};
    const int lane = tid & 63, w = tid >> 6;
    const int wm = w & 1, wn = w >> 1;

    // staging decode: chunk c = i*256+tid; row=c>>3, kchunk=c&7, swizzled source col
    const int s_row = tid >> 3;          // +64*i/... recomputed per i below
    (void)s_row;

    for (int k0 = 0; k0 < K; k0 += 64) {
#pragma unroll
        for (int i = 0; i < 4; i++) {
            int c = i * 256 + tid;
            int row = c >> 3;
            int g = (c & 7) ^ (row & 7);   // swizzled global 16B-chunk column
            const unsigned short* ga = &A[(long)(m0 + row) * lda + k0 + g * 8];
            load_lds16(ga, &As[c * 8]);
            const unsigned short* gb = &B[(long)(n0 + row) * ldb + k0 + g * 8];
            load_lds16(gb, &Bs[c * 8]);
        }
        __syncthreads();
#pragma unroll
        for (int kk = 0; kk < 64; kk += 32) {
            const int gc = (kk >> 3) + (lane >> 4);  // global 16B-chunk col for this frag
            bf16x8 af[4], bf[4];
#pragma unroll
            for (int i = 0; i < 4; i++) {
                int r = wm * 64 + i * 16 + (lane & 15);
                af[i] = *(const bf16x8*)&As[r * 64 + ((gc ^ (r & 7)) << 3)];
            }
#pragma unroll
            for (int j = 0; j < 4; j++) {
                int r = wn * 64 + j * 16 + (lane & 15);
                bf[j] = *(const bf16x8*)&Bs[r * 64 + ((gc ^ (r & 7)) << 3)];
            }
#pragma unroll
            for (int i = 0; i < 4; i++)
#pragma unroll
                for (int j = 0; j < 4; j++)
                    acc[i][j] = __builtin_amdgcn_mfma_f32_16x16x32_bf16(af[i], bf[j], acc[i][j], 0, 0, 0);
        }
        __syncthreads();
    }

    float* Cf = (float*)Cv;
    unsigned short* Ch = (unsigned short*)Cv;
    const long cbase = (long)z * c_z;
#pragma unroll
    for (int i = 0; i < 4; i++)
#pragma unroll
        for (int j = 0; j < 4; j++) {
            int col = n0 + wn * 64 + j * 16 + (lane & 15);
            int rbase = m0 + wm * 64 + i * 16 + ((lane >> 4) * 4);
            float bb = bias ? bias[col] : 0.f;
#pragma unroll
            for (int r = 0; r < 4; r++) {
                int row = rbase + r;
                float v = acc[i][j][r] + bb;
                if (GELU) v = 0.5f * v * (1.f + erff(v * 0.70710678118654752f));
                long off = cbase + (long)row * ldc + col;
                if (OUT_BF16) Ch[off] = f2bf(v);
                else Cf[off] = v;
            }
        }
}

// ---------------- 64x64 GEMM (kept for G5: per-head N=64) ----------------
template <bool OUT_BF16, bool GELU, bool FLAG>
__global__ __launch_bounds__(256) void gemm_bt(
    const unsigned short* __restrict__ A, const unsigned short* __restrict__ B,
    void* __restrict__ Cv, const float* __restrict__ bias, const float* __restrict__ flag,
    int N, int K, int lda, int ldc,
    long a_z, long b_z, long c_z, int bias_z) {
    const int z = blockIdx.z;
    A += (long)z * a_z;
    B += (long)z * b_z;
    const int tid = threadIdx.x;
    const int m0 = blockIdx.y * 64, n0 = blockIdx.x * 64;
    __shared__ __attribute__((aligned(16))) unsigned short As[64][72];
    __shared__ __attribute__((aligned(16))) unsigned short Bs[64][72];
    f32x4 acc[2][2] = {};
    const int lane = tid & 63, w = tid >> 6;
    const int wm = w & 1, wn = w >> 1;
    const int ar = tid >> 3;
    const int ac = (tid & 7) * 8;

    for (int k0 = 0; k0 < K; k0 += 64) {
#pragma unroll
        for (int r = 0; r < 2; r++) {
            int row = ar + r * 32;
            us8 av = *(const us8*)&A[(long)(m0 + row) * lda + k0 + ac];
            *(us8*)&As[row][ac] = av;
            us8 bv = *(const us8*)&B[(long)(n0 + row) * K + k0 + ac];
            *(us8*)&Bs[row][ac] = bv;
        }
        __syncthreads();
#pragma unroll
        for (int kk = 0; kk < 64; kk += 32) {
            int kf = kk + (lane >> 4) * 8;
            bf16x8 a0 = *(const bf16x8*)&As[wm * 32 + (lane & 15)][kf];
            bf16x8 a1 = *(const bf16x8*)&As[wm * 32 + 16 + (lane & 15)][kf];
            bf16x8 b0 = *(const bf16x8*)&Bs[wn * 32 + (lane & 15)][kf];
            bf16x8 b1 = *(const bf16x8*)&Bs[wn * 32 + 16 + (lane & 15)][kf];
            acc[0][0] = __builtin_amdgcn_mfma_f32_16x16x32_bf16(a0, b0, acc[0][0], 0, 0, 0);
            acc[0][1] = __builtin_amdgcn_mfma_f32_16x16x32_bf16(a0, b1, acc[0][1], 0, 0, 0);
            acc[1][0] = __builtin_amdgcn_mfma_f32_16x16x32_bf16(a1, b0, acc[1][0], 0, 0, 0);
            acc[1][1] = __builtin_amdgcn_mfma_f32_16x16x32_bf16(a1, b1, acc[1][1], 0, 0, 0);
        }
        __syncthreads();
    }

    float* Cf = (float*)Cv;
    unsigned short* Ch = (unsigned short*)Cv;
    const long cbase = (long)z * c_z;
#pragma unroll
    for (int tm = 0; tm < 2; tm++)
#pragma unroll
        for (int tn = 0; tn < 2; tn++) {
            int col = n0 + wn * 32 + tn * 16 + (lane & 15);
            int rbase = m0 + wm * 32 + tm * 16 + ((lane >> 4) * 4);
            float bb = bias ? bias[(long)z * bias_z + col] : 0.f;
#pragma unroll
            for (int r = 0; r < 4; r++) {
                int row = rbase + r;
                float v = acc[tm][tn][r] + bb;
                if (GELU) v = 0.5f * v * (1.f + erff(v * 0.70710678118654752f));
                if (FLAG) v *= flag[row];
                long off = cbase + (long)row * ldc + col;
                if (OUT_BF16) Ch[off] = f2bf(v);
                else Cf[off] = v;
            }
        }
}

// ---------------- qbk[t,h] = sum_d q[t,h,d] * bk[h*64+d] ----------------
__global__ __launch_bounds__(256) void qbk_kernel(const unsigned short* __restrict__ Qb,
                                                  const float* __restrict__ bk,
                                                  float* __restrict__ qbk, long npair) {
    int lane = threadIdx.x & 63, w = threadIdx.x >> 6;
    long p = (long)blockIdx.x * 4 + w;
    if (p >= npair) return;
    long t = p / 12;
    int h = (int)(p - t * 12);
    float v = bf2f(Qb[t * HIDN + h * 64 + lane]) * bk[h * 64 + lane];
    for (int o = 32; o; o >>= 1) v += __shfl_down(v, o);
    if (lane == 0) qbk[p] = v;
}

// ---------------- fused attention: all-bf16 LDS ----------------
#define LDP 776
__global__ __launch_bounds__(256) void attn_kernel(
    const float* __restrict__ cands, unsigned short* __restrict__ qkcw,
    const void* __restrict__ maskp, const int* __restrict__ mode,
    const float* __restrict__ qbk, float* __restrict__ allm, long t0) {
    const int tid = threadIdx.x;
    const long tl = blockIdx.x;
    const long t = t0 + tl;
    __shared__ __attribute__((aligned(16))) unsigned short c_s[NCAND][LDP];
    __shared__ __attribute__((aligned(16))) unsigned short qk_s[NHEAD][LDP];
    __shared__ float sc[NHEAD][NCAND];
    __shared__ float attn_s[NHEAD][NCAND];
    __shared__ int msk[NCAND];
    __shared__ float qb_s[NHEAD];

    const float4* c4 = (const float4*)(cands + t * NCAND * HIDN);
    for (int i = tid; i < NCAND * HIDN / 4; i += 256) {
        int n = i / (HIDN / 4), j4 = (i - n * (HIDN / 4)) * 4;
        float4 f = c4[i];
        us4 o; o[0] = f2bf(f.x); o[1] = f2bf(f.y); o[2] = f2bf(f.z); o[3] = f2bf(f.w);
        *(us4*)&c_s[n][j4] = o;
    }
    const us8* q8 = (const us8*)(qkcw + tl * (NHEAD * HIDN));
    for (int i = tid; i < NHEAD * HIDN / 8; i += 256) {
        int h = i / (HIDN / 8), j8 = (i - h * (HIDN / 8)) * 8;
        *(us8*)&qk_s[h][j8] = q8[i];
    }
    if (tid < NCAND) {
        int mm = *mode;
        long mi = t * NCAND + tid;
        int mv;
        if (mm == 1)      mv = ((const unsigned char*)maskp)[mi] != 0;
        else if (mm == 2) mv = ((const float*)maskp)[mi] != 0.f;
        else if (mm == 3) mv = ((const long long*)maskp)[mi] != 0;
        else              mv = ((const int*)maskp)[mi] != 0;
        msk[tid] = mv;
    }
    if (tid >= 64 && tid < 64 + NHEAD) qb_s[tid - 64] = qbk[tl * NHEAD + (tid - 64)];
    __syncthreads();

    const int lane = tid & 63, w = tid >> 6;
    for (int p = w; p < NHEAD * NCAND; p += 4) {
        int h = p >> 3, n = p & 7;
        float s = 0.f;
#pragma unroll
        for (int i = 0; i < 6; i++) {
            int j = 2 * lane + 128 * i;
            unsigned int ua = *(const unsigned int*)&qk_s[h][j];
            unsigned int ub = *(const unsigned int*)&c_s[n][j];
            s += lo_bf(ua) * lo_bf(ub) + hi_bf(ua) * hi_bf(ub);
        }
        for (int o = 32; o; o >>= 1) s += __shfl_down(s, o);
        if (lane == 0) sc[h][n] = msk[n] ? 1e-10f : (s + qb_s[h]) * 0.125f;
    }
    __syncthreads();

    if (tid < NHEAD) {
        int h = tid;
        float mx = -1e30f;
        for (int n = 0; n < NCAND; n++) mx = fmaxf(mx, sc[h][n]);
        float e[NCAND], sm = 0.f;
        for (int n = 0; n < NCAND; n++) { e[n] = expf(sc[h][n] - mx); sm += e[n]; }
        float inv = 1.f / sm;
        for (int n = 0; n < NCAND; n++) attn_s[h][n] = e[n] * inv;
    }
    if (tid == 64) {
        int a = 1;
        for (int n = 0; n < NCAND; n++) a &= msk[n];
        allm[tl] = a ? 0.f : 1.f;
    }
    __syncthreads();

    unsigned short* out = qkcw + tl * (NHEAD * HIDN);
    for (int i = tid; i < NHEAD * HIDN / 8; i += 256) {
        int h = i / (HIDN / 8), j8 = (i - h * (HIDN / 8)) * 8;
        float acc[8] = {0.f, 0.f, 0.f, 0.f, 0.f, 0.f, 0.f, 0.f};
#pragma unroll
        for (int n = 0; n < NCAND; n++) {
            us8 cv = *(const us8*)&c_s[n][j8];
            float a = attn_s[h][n];
#pragma unroll
            for (int k = 0; k < 8; k++) acc[k] += a * bf2f(cv[k]);
        }
        us8 o;
#pragma unroll
        for (int k = 0; k < 8; k++) o[k] = f2bf(acc[k]);
        ((us8*)out)[i] = o;
    }
}

// ---------------- residual + layernorm ----------------
__global__ __launch_bounds__(256) void ln_kernel(float* __restrict__ io, const float* __restrict__ x,
                                                 const float* __restrict__ gamma,
                                                 const float* __restrict__ beta, long t0) {
    const int tid = threadIdx.x;
    const long tl = blockIdx.x;
    const long t = t0 + tl;
    float* row = io + tl * HIDN;
    const float* xr = x + t * HIDN;
    float v[3];
#pragma unroll
    for (int i = 0; i < 3; i++) v[i] = row[tid + i * 256] + xr[tid + i * 256];
    __shared__ float red[4];
    const int lane = tid & 63, w = tid >> 6;
    float s = v[0] + v[1] + v[2];
    for (int o = 32; o; o >>= 1) s += __shfl_down(s, o);
    if (lane == 0) red[w] = s;
    __syncthreads();
    float mu = (red[0] + red[1] + red[2] + red[3]) * (1.f / HIDN);
    __syncthreads();
    float d0 = v[0] - mu, d1 = v[1] - mu, d2 = v[2] - mu;
    float q = d0 * d0 + d1 * d1 + d2 * d2;
    for (int o = 32; o; o >>= 1) q += __shfl_down(q, o);
    if (lane == 0) red[w] = q;
    __syncthreads();
    float var = (red[0] + red[1] + red[2] + red[3]) * (1.f / HIDN);
    float inv = rsqrtf(var + 1e-12f);
#pragma unroll
    for (int i = 0; i < 3; i++) {
        int j = tid + i * 256;
        row[j] = (v[i] - mu) * inv * gamma[j] + beta[j];
    }
}

// ---------------- launcher ----------------
extern "C" void kernel_launch(void* const* d_in, const int* in_sizes, int n_in,
                              void* d_out, int out_size, void* d_ws, size_t ws_size,
                              hipStream_t stream) {
    const float* x     = (const float*)d_in[0];
    const float* cands = (const float*)d_in[1];
    const void*  maskp = d_in[2];
    const float* Wq = (const float*)d_in[3];
    const float* bq = (const float*)d_in[4];
    const float* Wk = (const float*)d_in[5];
    const float* bk = (const float*)d_in[6];
    const float* Wv = (const float*)d_in[7];
    const float* bv = (const float*)d_in[8];
    const float* Wt = (const float*)d_in[9];
    const float* bt = (const float*)d_in[10];
    const float* Wc = (const float*)d_in[11];
    const float* bc = (const float*)d_in[12];
    const float* gamma = (const float*)d_in[13];
    const float* beta  = (const float*)d_in[14];
    float* out = (float*)d_out;

    const long T = (long)in_sizes[0] / HIDN;  // 8192

    char* p = (char*)d_ws;
    auto alloc = [&](size_t bytes) -> char* {
        char* r = p;
        p += (bytes + 255) & ~(size_t)255;
        return r;
    };
    unsigned short* Wqb  = (unsigned short*)alloc((size_t)HIDN * HIDN * 2);
    unsigned short* Wk2b = (unsigned short*)alloc((size_t)HIDN * HIDN * 2);
    unsigned short* Wvb  = (unsigned short*)alloc((size_t)HIDN * HIDN * 2);
    unsigned short* Wtb  = (unsigned short*)alloc((size_t)FFDIM * HIDN * 2);
    unsigned short* Wcb  = (unsigned short*)alloc((size_t)HIDN * FFDIM * 2);
    int* mode = (int*)alloc(256);
    size_t fixed = (size_t)(p - (char*)d_ws);

    long TC = T;
    auto chunk_bytes = [&](long tc) -> size_t {
        return (size_t)tc * (HIDN * 2 + HIDN * 2 + NHEAD * 4 + 4 +
                             HIDN * 2 + NHEAD * HIDN * 2) + 8 * 256;
    };
    while (TC > 512 && fixed + chunk_bytes(TC) > ws_size) TC >>= 1;

    unsigned short* Xb   = (unsigned short*)alloc((size_t)TC * HIDN * 2);
    unsigned short* Qb   = (unsigned short*)alloc((size_t)TC * HIDN * 2);
    float* qbkb          = (float*)alloc((size_t)TC * NHEAD * 4);
    float* allm          = (float*)alloc((size_t)TC * 4);
    unsigned short* CTXb = (unsigned short*)alloc((size_t)TC * HIDN * 2);
    unsigned short* BIG  = (unsigned short*)alloc((size_t)TC * NHEAD * HIDN * 2);

    {
        long n4;
        n4 = (long)HIDN * HIDN / 4;
        cvt_f2b<<<dim3((n4 + 255) / 256), 256, 0, stream>>>(Wq, Wqb, n4);
        cvt_f2b<<<dim3((n4 + 255) / 256), 256, 0, stream>>>(Wv, Wvb, n4);
        n4 = (long)FFDIM * HIDN / 4;
        cvt_f2b<<<dim3((n4 + 255) / 256), 256, 0, stream>>>(Wt, Wtb, n4);
        cvt_f2b<<<dim3((n4 + 255) / 256), 256, 0, stream>>>(Wc, Wcb, n4);
        int nwk = NHEAD * HIDN * HDIM;
        cvt_wk<<<dim3((nwk + 255) / 256), 256, 0, stream>>>(Wk, Wk2b);
        mask_detect<<<dim3(1), 256, 0, stream>>>((const unsigned char*)maskp, (int)(T * NCAND), mode);
    }

    for (long t0 = 0; t0 < T; t0 += TC) {
        long n4 = TC * HIDN / 4;
        cvt_f2b<<<dim3((n4 + 255) / 256), 256, 0, stream>>>(x + t0 * HIDN, Xb, n4);

        // G1: Q = X @ Wq^T + bq
        gemm128<true, false><<<dim3(HIDN / 128, TC / 128, 1), 256, 0, stream>>>(
            Xb, Wqb, Qb, bq, HIDN, HIDN, HIDN, HIDN, 0, 0, 0);

        qbk_kernel<<<dim3((TC * NHEAD + 3) / 4), 256, 0, stream>>>(Qb, bk, qbkb, TC * NHEAD);

        // G2: qk_h = Q_h @ Wk_h  (per head, K=64)
        gemm128<true, false><<<dim3(HIDN / 128, TC / 128, NHEAD), 256, 0, stream>>>(
            Qb, Wk2b, BIG, nullptr, HDIM, HIDN, HDIM, NHEAD * HIDN,
            HDIM, (long)HIDN * HDIM, HIDN);

        attn_kernel<<<dim3(TC), 256, 0, stream>>>(cands, BIG, maskp, mode, qbkb, allm, t0);

        // G5: ctx_h = cw_h @ Wv_h^T + bv_h (per head, N=64) — 64-tile kernel
        gemm_bt<true, false, true><<<dim3(1, TC / 64, NHEAD), 256, 0, stream>>>(
            BIG, Wvb, CTXb, bv, allm, HDIM, HIDN, NHEAD * HIDN, HIDN,
            HIDN, (long)HDIM * HIDN, HDIM, HDIM);

        // G6: h1 = gelu(ctx @ Wt^T + bt)
        gemm128<true, true><<<dim3(FFDIM / 128, TC / 128, 1), 256, 0, stream>>>(
            CTXb, Wtb, BIG, bt, HIDN, HIDN, HIDN, FFDIM, 0, 0, 0);

        // G7: out = h1 @ Wc^T + bc (fp32)
        gemm128<false, false><<<dim3(HIDN / 128, TC / 128, 1), 256, 0, stream>>>(
            BIG, Wcb, out + t0 * HIDN, bc, FFDIM, FFDIM, FFDIM, HIDN, 0, 0, 0);

        ln_kernel<<<dim3(TC), 256, 0, stream>>>(out + t0 * HIDN, x, gamma, beta, t0);
    }
}

// Round 4
// 655.776 us; speedup vs baseline: 1.8363x; 1.2757x over previous
//
#include <hip/hip_runtime.h>

typedef __bf16 bf16x8 __attribute__((ext_vector_type(8)));
typedef float f32x4 __attribute__((ext_vector_type(4)));
typedef unsigned short us8 __attribute__((ext_vector_type(8)));
typedef unsigned short us4 __attribute__((ext_vector_type(4)));
typedef unsigned int u32;

#define HIDN 768
#define NHEAD 12
#define HDIM 64
#define FFDIM 3072
#define NCAND 8

__device__ __forceinline__ float bf2f(unsigned short u) {
    union { unsigned int i; float f; } x; x.i = ((unsigned int)u) << 16; return x.f;
}
__device__ __forceinline__ unsigned short f2bf(float f) {
    __bf16 h = (__bf16)f;
    return __builtin_bit_cast(unsigned short, h);
}

typedef const __attribute__((address_space(1))) u32* gas_p;
typedef __attribute__((address_space(3))) u32* las_p;
__device__ __forceinline__ void load_lds16(const unsigned short* g, unsigned short* l) {
    __builtin_amdgcn_global_load_lds((gas_p)(const void*)g, (las_p)(void*)l, 16, 0, 0);
}

// ---------------- conversion kernels ----------------
__global__ __launch_bounds__(256) void cvt_f2b(const float* __restrict__ src,
                                               unsigned short* __restrict__ dst, long n4) {
    long i = (long)blockIdx.x * 256 + threadIdx.x;
    if (i >= n4) return;
    float4 f = ((const float4*)src)[i];
    us4 o; o[0] = f2bf(f.x); o[1] = f2bf(f.y); o[2] = f2bf(f.z); o[3] = f2bf(f.w);
    *(us4*)&dst[i * 4] = o;
}

// Wk2[h][j][d] = Wk[(h*64+d)*768 + j]  — coalesced via LDS transpose tile
__global__ __launch_bounds__(256) void cvt_wk(const float* __restrict__ Wk,
                                              unsigned short* __restrict__ Wk2) {
    __shared__ float t[64][65];
    const int bx = blockIdx.x;
    const int h = bx / (HIDN / 64), jt = bx % (HIDN / 64);
    const int tid = threadIdx.x;
    int rj = tid & 63, rd = tid >> 6;
    for (int d = rd; d < 64; d += 4)
        t[d][rj] = Wk[(long)(h * 64 + d) * HIDN + jt * 64 + rj];
    __syncthreads();
    int wd = tid & 63, wj = tid >> 6;
    for (int j = wj; j < 64; j += 4)
        Wk2[((long)h * HIDN + jt * 64 + j) * 64 + wd] = f2bf(t[wd][j]);
}

// ---------------- mask dtype detection (parallel) ----------------
__global__ void zero_flags(int* __restrict__ f) {
    if (threadIdx.x < 3) f[threadIdx.x] = 0;
}
// flags[0]: nz at j%4==1 ; flags[1]: nz at j%4 in {2,3} ; flags[2]: nz at j%8==4
__global__ __launch_bounds__(256) void mask_scan(const unsigned char* __restrict__ m,
                                                 int nbytes, int* __restrict__ flags) {
    int a0 = 0, a1 = 0, a2 = 0;
    for (int i = blockIdx.x * 256 + threadIdx.x; i < nbytes; i += gridDim.x * 256) {
        if (m[i]) {
            int r4 = i & 3, r8 = i & 7;
            if (r4 == 1) a0 = 1;
            if (r4 >= 2) a1 = 1;
            if (r8 == 4) a2 = 1;
        }
    }
    if (a0) atomicOr(&flags[0], 1);
    if (a1) atomicOr(&flags[1], 1);
    if (a2) atomicOr(&flags[2], 1);
}

// ============ m97-style GEMM: C(M,N) = A(M,K) @ B(N,K)^T + bias ============
// M-tile = AI*32, N-tile = 128, BK=64, 256 threads (2x2 waves),
// global_load_lds width=16, XOR-swizzled 16B chunks (conflict-free ds_read_b128).
template <bool OUT_BF16, bool GELU, int AI>
__global__ __launch_bounds__(256) void gemm128(
    const unsigned short* __restrict__ A, const unsigned short* __restrict__ B,
    void* __restrict__ Cv, const float* __restrict__ bias,
    int K, int lda, int ldb, int ldc,
    long a_z, long b_z, long c_z) {
    const int z = blockIdx.z;
    A += (long)z * a_z;
    B += (long)z * b_z;
    const int tid = threadIdx.x;
    const int m0 = blockIdx.y * (AI * 32), n0 = blockIdx.x * 128;
    __shared__ __attribute__((aligned(16))) unsigned short As[AI * 32 * 64];
    __shared__ __attribute__((aligned(16))) unsigned short Bs[128 * 64];
    f32x4 acc[AI][4] = {};
    const int lane = tid & 63, w = tid >> 6;
    const int wm = w & 1, wn = w >> 1;

    for (int k0 = 0; k0 < K; k0 += 64) {
#pragma unroll
        for (int i = 0; i < AI; i++) {
            int c = i * 256 + tid;
            int row = c >> 3;
            int g = (c & 7) ^ (row & 7);
            load_lds16(&A[(long)(m0 + row) * lda + k0 + g * 8], &As[c * 8]);
        }
#pragma unroll
        for (int i = 0; i < 4; i++) {
            int c = i * 256 + tid;
            int row = c >> 3;
            int g = (c & 7) ^ (row & 7);
            load_lds16(&B[(long)(n0 + row) * ldb + k0 + g * 8], &Bs[c * 8]);
        }
        __syncthreads();
#pragma unroll
        for (int kk = 0; kk < 64; kk += 32) {
            const int gc = (kk >> 3) + (lane >> 4);
            bf16x8 af[AI], bfr[4];
#pragma unroll
            for (int i = 0; i < AI; i++) {
                int r = wm * (AI * 16) + i * 16 + (lane & 15);
                af[i] = *(const bf16x8*)&As[r * 64 + ((gc ^ (r & 7)) << 3)];
            }
#pragma unroll
            for (int j = 0; j < 4; j++) {
                int r = wn * 64 + j * 16 + (lane & 15);
                bfr[j] = *(const bf16x8*)&Bs[r * 64 + ((gc ^ (r & 7)) << 3)];
            }
#pragma unroll
            for (int i = 0; i < AI; i++)
#pragma unroll
                for (int j = 0; j < 4; j++)
                    acc[i][j] = __builtin_amdgcn_mfma_f32_16x16x32_bf16(af[i], bfr[j], acc[i][j], 0, 0, 0);
        }
        __syncthreads();
    }

    float* Cf = (float*)Cv;
    unsigned short* Ch = (unsigned short*)Cv;
    const long cbase = (long)z * c_z;
#pragma unroll
    for (int i = 0; i < AI; i++)
#pragma unroll
        for (int j = 0; j < 4; j++) {
            int col = n0 + wn * 64 + j * 16 + (lane & 15);
            int rbase = m0 + wm * (AI * 16) + i * 16 + ((lane >> 4) * 4);
            float bb = bias ? bias[col] : 0.f;
#pragma unroll
            for (int r = 0; r < 4; r++) {
                int row = rbase + r;
                float v = acc[i][j][r] + bb;
                if (GELU) v = 0.5f * v * (1.f + erff(v * 0.70710678118654752f));
                long off = cbase + (long)row * ldc + col;
                if (OUT_BF16) Ch[off] = f2bf(v);
                else Cf[off] = v;
            }
        }
}

// ---------------- 64x64 GEMM (kept for G5: per-head N=64) ----------------
template <bool OUT_BF16, bool GELU, bool FLAG>
__global__ __launch_bounds__(256) void gemm_bt(
    const unsigned short* __restrict__ A, const unsigned short* __restrict__ B,
    void* __restrict__ Cv, const float* __restrict__ bias, const float* __restrict__ flag,
    int N, int K, int lda, int ldc,
    long a_z, long b_z, long c_z, int bias_z) {
    const int z = blockIdx.z;
    A += (long)z * a_z;
    B += (long)z * b_z;
    const int tid = threadIdx.x;
    const int m0 = blockIdx.y * 64, n0 = blockIdx.x * 64;
    __shared__ __attribute__((aligned(16))) unsigned short As[64][72];
    __shared__ __attribute__((aligned(16))) unsigned short Bs[64][72];
    f32x4 acc[2][2] = {};
    const int lane = tid & 63, w = tid >> 6;
    const int wm = w & 1, wn = w >> 1;
    const int ar = tid >> 3;
    const int ac = (tid & 7) * 8;

    for (int k0 = 0; k0 < K; k0 += 64) {
#pragma unroll
        for (int r = 0; r < 2; r++) {
            int row = ar + r * 32;
            us8 av = *(const us8*)&A[(long)(m0 + row) * lda + k0 + ac];
            *(us8*)&As[row][ac] = av;
            us8 bv = *(const us8*)&B[(long)(n0 + row) * K + k0 + ac];
            *(us8*)&Bs[row][ac] = bv;
        }
        __syncthreads();
#pragma unroll
        for (int kk = 0; kk < 64; kk += 32) {
            int kf = kk + (lane >> 4) * 8;
            bf16x8 a0 = *(const bf16x8*)&As[wm * 32 + (lane & 15)][kf];
            bf16x8 a1 = *(const bf16x8*)&As[wm * 32 + 16 + (lane & 15)][kf];
            bf16x8 b0 = *(const bf16x8*)&Bs[wn * 32 + (lane & 15)][kf];
            bf16x8 b1 = *(const bf16x8*)&Bs[wn * 32 + 16 + (lane & 15)][kf];
            acc[0][0] = __builtin_amdgcn_mfma_f32_16x16x32_bf16(a0, b0, acc[0][0], 0, 0, 0);
            acc[0][1] = __builtin_amdgcn_mfma_f32_16x16x32_bf16(a0, b1, acc[0][1], 0, 0, 0);
            acc[1][0] = __builtin_amdgcn_mfma_f32_16x16x32_bf16(a1, b0, acc[1][0], 0, 0, 0);
            acc[1][1] = __builtin_amdgcn_mfma_f32_16x16x32_bf16(a1, b1, acc[1][1], 0, 0, 0);
        }
        __syncthreads();
    }

    float* Cf = (float*)Cv;
    unsigned short* Ch = (unsigned short*)Cv;
    const long cbase = (long)z * c_z;
#pragma unroll
    for (int tm = 0; tm < 2; tm++)
#pragma unroll
        for (int tn = 0; tn < 2; tn++) {
            int col = n0 + wn * 32 + tn * 16 + (lane & 15);
            int rbase = m0 + wm * 32 + tm * 16 + ((lane >> 4) * 4);
            float bb = bias ? bias[(long)z * bias_z + col] : 0.f;
#pragma unroll
            for (int r = 0; r < 4; r++) {
                int row = rbase + r;
                float v = acc[tm][tn][r] + bb;
                if (GELU) v = 0.5f * v * (1.f + erff(v * 0.70710678118654752f));
                if (FLAG) v *= flag[row];
                long off = cbase + (long)row * ldc + col;
                if (OUT_BF16) Ch[off] = f2bf(v);
                else Cf[off] = v;
            }
        }
}

// ---------------- qbk[t,h] = sum_d q[t,h,d] * bk[h*64+d] ----------------
__global__ __launch_bounds__(256) void qbk_kernel(const unsigned short* __restrict__ Qb,
                                                  const float* __restrict__ bk,
                                                  float* __restrict__ qbk, long npair) {
    int lane = threadIdx.x & 63, w = threadIdx.x >> 6;
    long p = (long)blockIdx.x * 4 + w;
    if (p >= npair) return;
    long t = p / 12;
    int h = (int)(p - t * 12);
    float v = bf2f(Qb[t * HIDN + h * 64 + lane]) * bk[h * 64 + lane];
    for (int o = 32; o; o >>= 1) v += __shfl_down(v, o);
    if (lane == 0) qbk[p] = v;
}

// ---------------- fused attention v3: MFMA scores ----------------
// LDS layout: single buffer; c rows [0,8) then qk rows [0,16) (4 pad rows so
// MFMA A-frag lanes 12-15 read valid LDS; B-frag rows 8-15 land in qk rows 0-7,
// garbage only reaches discarded C cols/rows).
#define LDP 776
__global__ __launch_bounds__(256) void attn_kernel(
    const float* __restrict__ cands, unsigned short* __restrict__ qkcw,
    const void* __restrict__ maskp, const int* __restrict__ flags,
    const float* __restrict__ qbk, float* __restrict__ allm, long t0) {
    const int tid = threadIdx.x;
    const long tl = blockIdx.x;
    const long t = t0 + tl;
    __shared__ __attribute__((aligned(16))) unsigned short buf[(NCAND + 16) * LDP];
    unsigned short* c_s = buf;                 // 8 rows
    unsigned short* qk_s = buf + NCAND * LDP;  // 12 valid + 4 pad rows
    __shared__ float sc[NHEAD][NCAND];
    __shared__ float attn_s[NHEAD][NCAND];
    __shared__ float scr[16][16];
    __shared__ int msk[NCAND];
    __shared__ float qb_s[NHEAD];

    // stage c: fp32 global -> bf16 LDS
    const float4* c4 = (const float4*)(cands + t * NCAND * HIDN);
    for (int i = tid; i < NCAND * HIDN / 4; i += 256) {
        int n = i / (HIDN / 4), j4 = (i - n * (HIDN / 4)) * 4;
        float4 f = c4[i];
        us4 o; o[0] = f2bf(f.x); o[1] = f2bf(f.y); o[2] = f2bf(f.z); o[3] = f2bf(f.w);
        *(us4*)&c_s[n * LDP + j4] = o;
    }
    // stage qk
    const us8* q8 = (const us8*)(qkcw + tl * (NHEAD * HIDN));
    for (int i = tid; i < NHEAD * HIDN / 8; i += 256) {
        int h = i / (HIDN / 8), j8 = (i - h * (HIDN / 8)) * 8;
        *(us8*)&qk_s[h * LDP + j8] = q8[i];
    }
    if (tid < NCAND) {
        int mm = flags[0] ? 1 : (flags[1] ? 2 : (flags[2] ? 0 : 3));
        long mi = t * NCAND + tid;
        int mv;
        if (mm == 1)      mv = ((const unsigned char*)maskp)[mi] != 0;
        else if (mm == 2) mv = ((const float*)maskp)[mi] != 0.f;
        else if (mm == 3) mv = ((const long long*)maskp)[mi] != 0;
        else              mv = ((const int*)maskp)[mi] != 0;
        msk[tid] = mv;
    }
    if (tid >= 64 && tid < 64 + NHEAD) qb_s[tid - 64] = qbk[tl * NHEAD + (tid - 64)];
    __syncthreads();

    const int lane = tid & 63, w = tid >> 6;
    // scores via MFMA on wave 0: C[h][n] = qk[h,:] . c[n,:]
    if (w == 0) {
        const unsigned short* arow = &qk_s[(lane & 15) * LDP + (lane >> 4) * 8];
        const unsigned short* brow = &c_s[(lane & 15) * LDP + (lane >> 4) * 8];
        f32x4 a0 = {}, a1 = {};
#pragma unroll
        for (int k = 0; k < HIDN; k += 64) {
            bf16x8 afa = *(const bf16x8*)&arow[k];
            bf16x8 bfa = *(const bf16x8*)&brow[k];
            bf16x8 afb = *(const bf16x8*)&arow[k + 32];
            bf16x8 bfb = *(const bf16x8*)&brow[k + 32];
            a0 = __builtin_amdgcn_mfma_f32_16x16x32_bf16(afa, bfa, a0, 0, 0, 0);
            a1 = __builtin_amdgcn_mfma_f32_16x16x32_bf16(afb, bfb, a1, 0, 0, 0);
        }
        int n = lane & 15;
#pragma unroll
        for (int r = 0; r < 4; r++) {
            int h = (lane >> 4) * 4 + r;
            scr[h][n] = a0[r] + a1[r];
        }
    }
    if (tid == 64) {
        int a = 1;
        for (int n = 0; n < NCAND; n++) a &= msk[n];
        allm[tl] = a ? 0.f : 1.f;
    }
    __syncthreads();

    if (tid < NHEAD) {
        int h = tid;
        float e[NCAND], sm = 0.f, mx = -1e30f;
        float svals[NCAND];
        for (int n = 0; n < NCAND; n++) {
            svals[n] = msk[n] ? 1e-10f : (scr[h][n] + qb_s[h]) * 0.125f;
            mx = fmaxf(mx, svals[n]);
        }
        for (int n = 0; n < NCAND; n++) { e[n] = expf(svals[n] - mx); sm += e[n]; }
        float inv = 1.f / sm;
        for (int n = 0; n < NCAND; n++) attn_s[h][n] = e[n] * inv;
    }
    __syncthreads();

    // cw: out[h][j..j+7] = sum_n attn[h][n] * c[n][j..j+7]
    unsigned short* out = qkcw + tl * (NHEAD * HIDN);
    for (int i = tid; i < NHEAD * HIDN / 8; i += 256) {
        int h = i / (HIDN / 8), j8 = (i - h * (HIDN / 8)) * 8;
        float acc[8] = {0.f, 0.f, 0.f, 0.f, 0.f, 0.f, 0.f, 0.f};
#pragma unroll
        for (int n = 0; n < NCAND; n++) {
            us8 cv = *(const us8*)&c_s[n * LDP + j8];
            float a = attn_s[h][n];
#pragma unroll
            for (int k = 0; k < 8; k++) acc[k] += a * bf2f(cv[k]);
        }
        us8 o;
#pragma unroll
        for (int k = 0; k < 8; k++) o[k] = f2bf(acc[k]);
        ((us8*)out)[i] = o;
    }
}

// ---------------- residual + layernorm ----------------
__global__ __launch_bounds__(256) void ln_kernel(float* __restrict__ io, const float* __restrict__ x,
                                                 const float* __restrict__ gamma,
                                                 const float* __restrict__ beta, long t0) {
    const int tid = threadIdx.x;
    const long tl = blockIdx.x;
    const long t = t0 + tl;
    float* row = io + tl * HIDN;
    const float* xr = x + t * HIDN;
    float v[3];
#pragma unroll
    for (int i = 0; i < 3; i++) v[i] = row[tid + i * 256] + xr[tid + i * 256];
    __shared__ float red[4];
    const int lane = tid & 63, w = tid >> 6;
    float s = v[0] + v[1] + v[2];
    for (int o = 32; o; o >>= 1) s += __shfl_down(s, o);
    if (lane == 0) red[w] = s;
    __syncthreads();
    float mu = (red[0] + red[1] + red[2] + red[3]) * (1.f / HIDN);
    __syncthreads();
    float d0 = v[0] - mu, d1 = v[1] - mu, d2 = v[2] - mu;
    float q = d0 * d0 + d1 * d1 + d2 * d2;
    for (int o = 32; o; o >>= 1) q += __shfl_down(q, o);
    if (lane == 0) red[w] = q;
    __syncthreads();
    float var = (red[0] + red[1] + red[2] + red[3]) * (1.f / HIDN);
    float inv = rsqrtf(var + 1e-12f);
#pragma unroll
    for (int i = 0; i < 3; i++) {
        int j = tid + i * 256;
        row[j] = (v[i] - mu) * inv * gamma[j] + beta[j];
    }
}

// ---------------- launcher ----------------
extern "C" void kernel_launch(void* const* d_in, const int* in_sizes, int n_in,
                              void* d_out, int out_size, void* d_ws, size_t ws_size,
                              hipStream_t stream) {
    const float* x     = (const float*)d_in[0];
    const float* cands = (const float*)d_in[1];
    const void*  maskp = d_in[2];
    const float* Wq = (const float*)d_in[3];
    const float* bq = (const float*)d_in[4];
    const float* Wk = (const float*)d_in[5];
    const float* bk = (const float*)d_in[6];
    const float* Wv = (const float*)d_in[7];
    const float* bv = (const float*)d_in[8];
    const float* Wt = (const float*)d_in[9];
    const float* bt = (const float*)d_in[10];
    const float* Wc = (const float*)d_in[11];
    const float* bc = (const float*)d_in[12];
    const float* gamma = (const float*)d_in[13];
    const float* beta  = (const float*)d_in[14];
    float* out = (float*)d_out;

    const long T = (long)in_sizes[0] / HIDN;  // 8192

    char* p = (char*)d_ws;
    auto alloc = [&](size_t bytes) -> char* {
        char* r = p;
        p += (bytes + 255) & ~(size_t)255;
        return r;
    };
    unsigned short* Wqb  = (unsigned short*)alloc((size_t)HIDN * HIDN * 2);
    unsigned short* Wk2b = (unsigned short*)alloc((size_t)HIDN * HIDN * 2);
    unsigned short* Wvb  = (unsigned short*)alloc((size_t)HIDN * HIDN * 2);
    unsigned short* Wtb  = (unsigned short*)alloc((size_t)FFDIM * HIDN * 2);
    unsigned short* Wcb  = (unsigned short*)alloc((size_t)HIDN * FFDIM * 2);
    int* flags = (int*)alloc(256);
    size_t fixed = (size_t)(p - (char*)d_ws);

    long TC = T;
    auto chunk_bytes = [&](long tc) -> size_t {
        return (size_t)tc * (HIDN * 2 + HIDN * 2 + NHEAD * 4 + 4 +
                             HIDN * 2 + NHEAD * HIDN * 2) + 8 * 256;
    };
    while (TC > 512 && fixed + chunk_bytes(TC) > ws_size) TC >>= 1;

    unsigned short* Xb   = (unsigned short*)alloc((size_t)TC * HIDN * 2);
    unsigned short* Qb   = (unsigned short*)alloc((size_t)TC * HIDN * 2);
    float* qbkb          = (float*)alloc((size_t)TC * NHEAD * 4);
    float* allm          = (float*)alloc((size_t)TC * 4);
    unsigned short* CTXb = (unsigned short*)alloc((size_t)TC * HIDN * 2);
    unsigned short* BIG  = (unsigned short*)alloc((size_t)TC * NHEAD * HIDN * 2);

    {
        long n4;
        n4 = (long)HIDN * HIDN / 4;
        cvt_f2b<<<dim3((n4 + 255) / 256), 256, 0, stream>>>(Wq, Wqb, n4);
        cvt_f2b<<<dim3((n4 + 255) / 256), 256, 0, stream>>>(Wv, Wvb, n4);
        n4 = (long)FFDIM * HIDN / 4;
        cvt_f2b<<<dim3((n4 + 255) / 256), 256, 0, stream>>>(Wt, Wtb, n4);
        cvt_f2b<<<dim3((n4 + 255) / 256), 256, 0, stream>>>(Wc, Wcb, n4);
        cvt_wk<<<dim3(NHEAD * (HIDN / 64)), 256, 0, stream>>>(Wk, Wk2b);
        zero_flags<<<dim3(1), 64, 0, stream>>>(flags);
        mask_scan<<<dim3(256), 256, 0, stream>>>((const unsigned char*)maskp,
                                                 (int)(T * NCAND), flags);
    }

    for (long t0 = 0; t0 < T; t0 += TC) {
        long n4 = TC * HIDN / 4;
        cvt_f2b<<<dim3((n4 + 255) / 256), 256, 0, stream>>>(x + t0 * HIDN, Xb, n4);

        // G1: Q = X @ Wq^T + bq   (M-tile 64 -> 768 blocks)
        gemm128<true, false, 2><<<dim3(HIDN / 128, TC / 64, 1), 256, 0, stream>>>(
            Xb, Wqb, Qb, bq, HIDN, HIDN, HIDN, HIDN, 0, 0, 0);

        qbk_kernel<<<dim3((TC * NHEAD + 3) / 4), 256, 0, stream>>>(Qb, bk, qbkb, TC * NHEAD);

        // G2: qk_h = Q_h @ Wk_h  (per head, K=64)
        gemm128<true, false, 4><<<dim3(HIDN / 128, TC / 128, NHEAD), 256, 0, stream>>>(
            Qb, Wk2b, BIG, nullptr, HDIM, HIDN, HDIM, NHEAD * HIDN,
            HDIM, (long)HIDN * HDIM, HIDN);

        attn_kernel<<<dim3(TC), 256, 0, stream>>>(cands, BIG, maskp, flags, qbkb, allm, t0);

        // G5: ctx_h = cw_h @ Wv_h^T + bv_h (per head, N=64) — 64-tile kernel
        gemm_bt<true, false, true><<<dim3(1, TC / 64, NHEAD), 256, 0, stream>>>(
            BIG, Wvb, CTXb, bv, allm, HDIM, HIDN, NHEAD * HIDN, HIDN,
            HIDN, (long)HDIM * HIDN, HDIM, HDIM);

        // G6: h1 = gelu(ctx @ Wt^T + bt)
        gemm128<true, true, 4><<<dim3(FFDIM / 128, TC / 128, 1), 256, 0, stream>>>(
            CTXb, Wtb, BIG, bt, HIDN, HIDN, HIDN, FFDIM, 0, 0, 0);

        // G7: out = h1 @ Wc^T + bc (fp32)  (M-tile 64 -> 768 blocks)
        gemm128<false, false, 2><<<dim3(HIDN / 128, TC / 64, 1), 256, 0, stream>>>(
            BIG, Wcb, out + t0 * HIDN, bc, FFDIM, FFDIM, FFDIM, HIDN, 0, 0, 0);

        ln_kernel<<<dim3(TC), 256, 0, stream>>>(out + t0 * HIDN, x, gamma, beta, t0);
    }
}